// Round 5
// baseline (174.673 us; speedup 1.0000x reference)
//
#include <hip/hip_runtime.h>
#include <stdint.h>
#include <math.h>

// RpnLoss: BATCH=4096 samples, A = 5*17*17 = 1445 anchors.
// R5: TWO waves per sample (half0: t=0..11, half1: t=12..22), 2 samples/block,
// grid 2048 -> 32 waves/CU (occupancy cap, was 16). Bulk state in per-sample
// LDS; compaction via LDS atomics (rare); phase work split across halves:
// half0 = histogram scan + boundary, half1 = positive ranking + reg loss.
// amdgpu_waves_per_eu(8) caps VGPR at 64 (live set ~40, no spill).
// PRNG (bit-exact, verified R1-R4): key_i = threefry((0,42),(0,i));
// kpos[n]=key_n, kneg[n]=key_{N+n}; draw j: r = (o0^o1 of threefry(key,(0,j)))>>9.

#define A_TOT 1445
#define NITER 23
#define SPB 2           // samples per block
#define BLOCK (SPB * 2 * 64)
#define POS_MAX 64
#define CAND_MAX 128

__device__ __forceinline__ void tf2x32(uint32_t k0, uint32_t k1, uint32_t x0, uint32_t x1,
                                       uint32_t& o0, uint32_t& o1)
{
  const uint32_t k2 = k0 ^ k1 ^ 0x1BD11BDAu;
  x0 += k0; x1 += k1;
#define TFR(r) { x0 += x1; x1 = __builtin_rotateleft32(x1, (r)); x1 ^= x0; }
  TFR(13) TFR(15) TFR(26) TFR(6)
  x0 += k1; x1 += k2 + 1u;
  TFR(17) TFR(29) TFR(16) TFR(24)
  x0 += k2; x1 += k0 + 2u;
  TFR(13) TFR(15) TFR(26) TFR(6)
  x0 += k0; x1 += k1 + 3u;
  TFR(17) TFR(29) TFR(16) TFR(24)
  x0 += k1; x1 += k2 + 4u;
  TFR(13) TFR(15) TFR(26) TFR(6)
  x0 += k2; x1 += k0 + 5u;
#undef TFR
  o0 = x0; o1 = x1;
}

// logaddexp(0,x) via HW exp/log; rel err ~2^-21 << 3e-2 threshold (passed R1-R4).
__device__ __forceinline__ float lae0(float x){
  return fmaxf(x, 0.0f) + __logf(1.0f + __expf(-fabsf(x)));
}

__global__ void __attribute__((amdgpu_waves_per_eu(8)))
__launch_bounds__(BLOCK) rpn_loss_kernel(
    const float* __restrict__ pred_cls, const float* __restrict__ pred_reg,
    const float* __restrict__ gt_bbox, const float* __restrict__ anchor_center,
    const float* __restrict__ anchor_corner,
    float* __restrict__ part,   // [3][N] partials: lc, lr, acc
    int N)
{
  __shared__ uint32_t s_rnm[SPB][A_TOT];    // (r<<2)|enc  enc: 2=pos 1=ignore 0=neg
  __shared__ uint32_t s_hist[SPB][256];
  __shared__ uint32_t s_pidx[SPB][POS_MAX];
  __shared__ float    s_pcls[SPB][POS_MAX];
  __shared__ uint32_t s_cand[SPB][CAND_MAX];
  __shared__ uint32_t s_cnt[SPB][4];        // 0=posCnt 1=candCnt 2=(Bb<<16)|m 3=n_neg
  __shared__ float    s_red[SPB][2][3];     // per-sample, per-half partials
  // LDS: 2*(5780+1024+256+256+512+16+24) = ~15.8 KB -> 8 blocks/CU fits.

  const int tid  = threadIdx.x;
  const int w    = tid >> 6;          // 0..3
  const int lane = tid & 63;
  const int s    = w >> 1;            // sample slot in block
  const int half = w & 1;
  const int n    = blockIdx.x * SPB + s;

  // ---- init: zero histogram + counters (128 threads/sample -> 2 bins each)
  s_hist[s][half * 128 + lane * 2 + 0] = 0u;
  s_hist[s][half * 128 + lane * 2 + 1] = 0u;
  if (half == 0 && lane < 4) s_cnt[s][lane] = 0u;

  const float g0 = gt_bbox[4 * n + 0];
  const float g1 = gt_bbox[4 * n + 1];
  const float g2 = gt_bbox[4 * n + 2];
  const float g3 = gt_bbox[4 * n + 3];
  const float area_a = (g2 - g0) * (g3 - g1);

  uint32_t kn0, kn1;
  tf2x32(0u, 42u, 0u, (uint32_t)(N + n), kn0, kn1);

  const float*  cls_base = pred_cls + (size_t)n * A_TOT;
  const float4* cornv = (const float4*)anchor_corner;

  __syncthreads();                                      // B0: LDS zeroed

  // ---- Phase A: IoU + neg-key hash -> LDS + histogram + pos compaction + acc
  float accc = 0.0f;
  const int t0 = half * 12, t1 = half ? NITER : 12;
  for (int t = t0; t < t1; t++){
    int j = lane + 64 * t;
    bool valid = (j < A_TOT);           // only t==22 partial (lane<37)
    int jc = valid ? j : (A_TOT - 1);
    float4 cr = cornv[jc];
    float c = cls_base[jc];
    float ltx = fmaxf(g0, cr.x), lty = fmaxf(g1, cr.y);
    float rbx = fminf(g2, cr.z), rby = fminf(g3, cr.w);
    float inter = fmaxf(rbx - ltx, 0.0f) * fmaxf(rby - lty, 0.0f);
    float area_b = (cr.z - cr.x) * (cr.w - cr.y);
    float iou = inter / (area_a + area_b - inter);
    bool pos = valid && (iou > 0.6f);
    bool neg = valid && (iou < 0.3f);
    uint32_t o0, o1;
    tf2x32(kn0, kn1, 0u, (uint32_t)j, o0, o1);
    uint32_t r = (o0 ^ o1) >> 9;        // 23-bit rank value
    uint32_t enc = pos ? 2u : (neg ? 0u : 1u);
    if (valid) s_rnm[s][j] = (r << 2) | enc;
    if (neg)   atomicAdd(&s_hist[s][r >> 15], 1u);
    if (pos){
      uint32_t id = atomicAdd(&s_cnt[s][0], 1u);
      if (id < POS_MAX){ s_pidx[s][id] = (uint32_t)j; s_pcls[s][id] = c; }
    }
    accc += (valid && ((c >= 0.6f) == pos)) ? 1.0f : 0.0f;
  }
  __syncthreads();                                      // B1: phase A complete

  const int n_pos = (int)s_cnt[s][0];   // raw (geometric max << POS_MAX)
  const int k_p = min(n_pos, 16);

  float lc = 0.0f, lr = 0.0f;
  if (half == 0){
    // ---- histogram scan (4 bins/lane + shuffle scan) + boundary bin
    int b = lane * 4;
    uint32_t v0 = s_hist[s][b], v1 = s_hist[s][b+1], v2 = s_hist[s][b+2], v3 = s_hist[s][b+3];
    uint32_t S0 = v0, S1 = S0 + v1, S2 = S1 + v2, S3 = S2 + v3;
    uint32_t x = S3;
    #pragma unroll
    for (int off = 1; off < 64; off <<= 1){
      uint32_t tmp = __shfl_up(x, off, 64);
      if (lane >= off) x += tmp;
    }
    uint32_t excl = x - S3;
    S0 += excl; S1 += excl; S2 += excl; S3 += excl;
    s_hist[s][b] = S3;                  // only bin-group cumsums needed below
    const int n_neg = (int)__shfl(S3, 63, 64);
    const int k_n = min(n_neg, (n_pos > 0) ? 3 * n_pos : 48);
    int Bb = 256, m = 0;
    if (k_n > 0){
      unsigned long long bal = __ballot(S3 >= (uint32_t)k_n);
      int fl = __ffsll(bal) - 1;
      uint32_t u0 = __shfl(S0, fl, 64), u1 = __shfl(S1, fl, 64), u2 = __shfl(S2, fl, 64);
      int sub = (u0 >= (uint32_t)k_n) ? 0 : ((u1 >= (uint32_t)k_n) ? 1 : ((u2 >= (uint32_t)k_n) ? 2 : 3));
      Bb = fl * 4 + sub;
      // count before bin Bb: cumsum of previous bin = S_{sub-1} at lane fl, or
      // group-cumsum of lane fl-1 (==__shfl(x,fl-1) but x holds incl; use S3@fl-1)
      uint32_t before;
      if (sub == 0) before = (fl == 0) ? 0u : __shfl(S3, fl - 1, 64);
      else          before = (sub == 1) ? u0 : ((sub == 2) ? u1 : u2);
      m = k_n - (int)before;
    }
    if (lane == 0){
      s_cnt[s][2] = ((uint32_t)Bb << 16) | (uint32_t)m;
      s_cnt[s][3] = (uint32_t)n_neg;
    }
  } else {
    // ---- positives: pos-key hash, shuffle ranking, bce + reg loss
    if (n_pos > 0){
      uint32_t kp0, kp1;
      tf2x32(0u, 42u, 0u, (uint32_t)n, kp0, kp1);
      uint32_t myr = 0u, myj = 0u; float myc = 0.0f;
      int npc = min(n_pos, POS_MAX);
      if (lane < npc){
        myj = s_pidx[s][lane];
        myc = s_pcls[s][lane];
        uint32_t o0, o1;
        tf2x32(kp0, kp1, 0u, myj, o0, o1);
        myr = (o0 ^ o1) >> 9;
      }
      int rank = 0;
      for (int l = 0; l < npc; l++){
        uint32_t r2 = __shfl(myr, l, 64), j2 = __shfl(myj, l, 64);
        if (lane < npc && (r2 < myr || (r2 == myr && j2 < myj))) rank++;
      }
      if (lane < npc){
        if (rank < k_p) lc += lae0(-myc);
        float gcx = (g0 + g2) * 0.5f, gcy = (g1 + g3) * 0.5f;
        float gw = g2 - g0, gh = g3 - g1;
        float4 ce = ((const float4*)anchor_center)[myj];
        const float* reg_base = pred_reg + (size_t)n * 4 * A_TOT;
        float q0 = (gcx - ce.x) / ce.z;
        float q1 = (gcy - ce.y) / ce.w;
        float q2 = __logf(gw / ce.z);
        float q3 = __logf(gh / ce.w);
        float d0 = reg_base[myj]             - q0;
        float d1 = reg_base[A_TOT + myj]     - q1;
        float d2 = reg_base[2 * A_TOT + myj] - q2;
        float d3 = reg_base[3 * A_TOT + myj] - q3;
        lr = d0 * d0 + d1 * d1 + d2 * d2 + d3 * d3;
      }
    }
  }
  __syncthreads();                                      // B2: Bb/m published

  const int n_neg = (int)s_cnt[s][3];
  const int k_n = min(n_neg, (n_pos > 0) ? 3 * n_pos : 48);
  const uint32_t bm = s_cnt[s][2];
  const int Bb = (int)(bm >> 16), m = (int)(bm & 0xFFFFu);

  // ---- negatives: both halves scan their t-range from LDS
  if (k_n > 0){
    for (int t = t0; t < t1; t++){
      int j = lane + 64 * t;
      bool valid = (j < A_TOT);
      uint32_t word = valid ? s_rnm[s][j] : 1u;   // enc=1 -> ignored
      bool isneg = (word & 3u) == 0u;
      int bin = (int)(word >> 17);
      if (isneg && bin < Bb) lc += lae0(cls_base[j]);    // L2-hot reload
      if (isneg && bin == Bb){
        uint32_t id = atomicAdd(&s_cnt[s][1], 1u);
        if (id < CAND_MAX)
          s_cand[s][id] = (((word >> 2) & 0x7FFFu) << 11) | (uint32_t)j;
      }
    }
  }
  __syncthreads();                                      // B3: candidates complete

  // ---- boundary-bin ranking (half0 only; L is small, ~Poisson(6))
  if (half == 0 && k_n > 0){
    const int L = min((int)s_cnt[s][1], CAND_MAX);
    for (int c2 = lane; c2 < L; c2 += 64){
      uint32_t my = s_cand[s][c2];
      int rank = 0;
      for (int l = 0; l < L; l++) rank += (s_cand[s][l] < my) ? 1 : 0;  // broadcast
      if (rank < m) lc += lae0(cls_base[my & 0x7FFu]);
    }
  }

  // ---- reduce: wave-reduce 3 floats, publish per-half, half0 lane0 combines
  float v0 = lc, v1 = lr, v2 = accc;
  #pragma unroll
  for (int off = 32; off > 0; off >>= 1){
    v0 += __shfl_down(v0, off, 64);
    v1 += __shfl_down(v1, off, 64);
    v2 += __shfl_down(v2, off, 64);
  }
  if (lane == 0){
    s_red[s][half][0] = v0; s_red[s][half][1] = v1; s_red[s][half][2] = v2;
  }
  __syncthreads();                                      // B4
  if (half == 0 && lane == 0){
    float slc = s_red[s][0][0] + s_red[s][1][0];
    float slr = s_red[s][0][1] + s_red[s][1][1];
    float sac = s_red[s][0][2] + s_red[s][1][2];
    int denom = k_p + k_n; if (denom < 1) denom = 1;
    part[n]         = slc / (float)denom;
    part[N + n]     = (n_pos > 0) ? (slr / (4.0f * (float)n_pos)) : 0.0f;
    part[2 * N + n] = sac * (1.0f / (float)A_TOT);
  }
}

__global__ void __launch_bounds__(256) reduce_kernel(const float* __restrict__ part,
                                                     float* __restrict__ out, int N)
{
  const int tid = threadIdx.x;
  float lc = 0.0f, lr = 0.0f, ac = 0.0f;
  for (int i = tid; i < N; i += 256){
    lc += part[i];
    lr += part[N + i];
    ac += part[2 * N + i];
  }
  __shared__ float s[12];
  #pragma unroll
  for (int off = 32; off > 0; off >>= 1){
    lc += __shfl_down(lc, off, 64);
    lr += __shfl_down(lr, off, 64);
    ac += __shfl_down(ac, off, 64);
  }
  const int wave = tid >> 6, lane = tid & 63;
  if (lane == 0){ s[wave] = lc; s[4 + wave] = lr; s[8 + wave] = ac; }
  __syncthreads();
  if (tid == 0){
    float LC = s[0] + s[1] + s[2] + s[3];
    float LR = s[4] + s[5] + s[6] + s[7];
    float AC = s[8] + s[9] + s[10] + s[11];
    float inv = 1.0f / (float)N;
    LC *= inv; LR *= inv; AC *= inv;
    out[0] = LC + LR;
    out[1] = LC;
    out[2] = LR;
    out[3] = AC;
  }
}

extern "C" void kernel_launch(void* const* d_in, const int* in_sizes, int n_in,
                              void* d_out, int out_size, void* d_ws, size_t ws_size,
                              hipStream_t stream)
{
  const float* pred_cls = (const float*)d_in[0];
  const float* pred_reg = (const float*)d_in[1];
  const float* gt_bbox  = (const float*)d_in[2];
  const float* a_center = (const float*)d_in[3];
  const float* a_corner = (const float*)d_in[4];
  float* part = (float*)d_ws;            // 3*N floats
  float* out  = (float*)d_out;

  const int N = in_sizes[2] / 4;         // 4096

  hipLaunchKernelGGL(rpn_loss_kernel, dim3(N / SPB), dim3(BLOCK), 0, stream,
                     pred_cls, pred_reg, gt_bbox, a_center, a_corner, part, N);
  hipLaunchKernelGGL(reduce_kernel, dim3(1), dim3(256), 0, stream, part, out, N);
}